// Round 13
// baseline (181.597 us; speedup 1.0000x reference)
//
#include <hip/hip_runtime.h>
#include <math.h>

#define Bn 16
#define Gn 2048
#define Cn 128
#define Kn 16
#define QB 32       // queries per block
#define SEG 129     // padded segment stride in float4 (2064B): bank quad = 4*sub%32,
                    // 2-way alias = free (m136); enables imm-offset ds_read (0 addr VALU)
#define AS 136      // A/H-tile row stride in bf16 elems: 272B = 17*16B (aligned, 2-way banks)

typedef __attribute__((ext_vector_type(8))) short bf16x8;
typedef __attribute__((ext_vector_type(4))) float f32x4;

__device__ __forceinline__ unsigned short f2bf(float x) {   // RNE fp32->bf16
    unsigned int u = __float_as_uint(x);
    unsigned int r = (u + 0x7fffu + ((u >> 16) & 1u)) >> 16;
    return (unsigned short)r;
}
__device__ __forceinline__ float bf2f(unsigned short h) {
    return __uint_as_float(((unsigned int)h) << 16);
}

__device__ __forceinline__ float med3f(float a, float b, float c) {
#if __has_builtin(__builtin_amdgcn_fmed3f)
    return __builtin_amdgcn_fmed3f(a, b, c);
#else
    return fmaxf(fminf(a, b), fminf(fmaxf(a, b), c));
#endif
}

// BIT-IDENTICAL in every phase (fp-consistent ranking incl. tie detection).
__device__ __forceinline__ float dist2(const float4 me, const float4 p) {
    float dot = fmaf(me.z, p.z, fmaf(me.y, p.y, me.x * p.x));
    return fmaf(-2.0f, dot, me.w + p.w);
}

__device__ __forceinline__ void ins16(float (&d)[16], float v) {
    float prev = d[0];
    d[0] = fminf(d[0], v);
    #pragma unroll
    for (int t = 1; t < 16; ++t) { float cur = d[t]; d[t] = med3f(v, prev, cur); prev = cur; }
}

// exact bitonic min-merge of sorted d[16] across the 16 lanes of a group.
// In-place: pairs (t,15-t) disjoint; both shfl reads precede writes.
__device__ __forceinline__ void merge16(float (&d)[16]) {
    #pragma unroll
    for (int m = 1; m < 16; m <<= 1) {
        #pragma unroll
        for (int t = 0; t < 8; ++t) {
            float sa = __shfl_xor(d[15 - t], m);    // partner's d[15-t]
            float sb = __shfl_xor(d[t], m);         // partner's d[t]
            d[t]      = fminf(d[t], sa);
            d[15 - t] = fminf(d[15 - t], sb);
        }
        #pragma unroll
        for (int k = 8; k; k >>= 1) {
            #pragma unroll
            for (int t = 0; t < 16; ++t)
                if (!(t & k)) {
                    float lo = fminf(d[t], d[t + k]);
                    float hi = fmaxf(d[t], d[t + k]);
                    d[t] = lo; d[t + k] = hi;
                }
        }
    }
}

__device__ __forceinline__ float gelu_exact(float x) {
    return 0.5f * x * (1.0f + erff(x * 0.70710678118654752440f));
}

// ---------------------------------------------------------------------------
// prep_w: W[k][n] fp32 -> Wt[n][k] split bf16 (hi/lo) in workspace.
// ws layout (ushorts): Wt1_hi[128*128] | Wt1_lo | Wt2_hi | Wt2_lo  (128 KB)
// ---------------------------------------------------------------------------
__global__ __launch_bounds__(256) void prep_w(const float* __restrict__ W1,
                                              const float* __restrict__ W2,
                                              unsigned short* __restrict__ ws) {
    int t = blockIdx.x * 256 + threadIdx.x;     // 0..16383 (grid 64)
    if (t < 16384) {
        int k = t >> 7, n = t & 127;
        float w = W1[t];
        unsigned short h = f2bf(w);
        unsigned short l = f2bf(w - bf2f(h));   // Dekker split: w-hi exact in fp32
        ws[n * 128 + k]          = h;
        ws[16384 + n * 128 + k]  = l;
        w = W2[t];
        h = f2bf(w);
        l = f2bf(w - bf2f(h));
        ws[32768 + n * 128 + k]  = h;
        ws[49152 + n * 128 + k]  = l;
    }
}

// ---------------------------------------------------------------------------
// Fully fused: KNN (sample->filter->select) + gather/L2-pool + MFMA MLP.
// 1024 blocks x 512 threads; b = x&15; chunk = x>>4 (0..63); 32 q/block.
// KNN: blocked per-lane segments, PADDED stride SEG=129 float4 so every
// phase-A/B LDS read is ds_read_b128 with a COMPILE-TIME immediate offset
// (zero address VALU); bank spread comes from the stride (4*sub%32, 2-way
// free per m136), not from the old "+c mod 128" arithmetic stagger.
// Survivor bit j <-> segment-local point j; out-index = sub*128+j,
// mem-index = out-index + sub. T0 = exact 16th of 32 per-lane-top-2
// candidates (R12, conservative; phase C recovers exact T => output exact).
// LDS 35072 B -> 4 blocks/CU. No min-waves bound (R4/R6: forcing it =>
// 32/32 unified split + spills).
// MLP: single f32x4 acc, sequential col-blocks, H in separate LDS region;
// split-bf16 MFMA 16x16x32 (Ahi*Bhi + Ahi*Blo + Alo*Bhi, err ~2^-17).
// ---------------------------------------------------------------------------
__global__ __launch_bounds__(512) void fused_kernel(const float* __restrict__ xyz,
                                                    const float* __restrict__ feat,
                                                    const float* __restrict__ b1,
                                                    const float* __restrict__ b2,
                                                    const unsigned short* __restrict__ wt,
                                                    float* __restrict__ out) {
    __shared__ __align__(16) float smem0[8768];       // 35072 B
    float4* pts = reinterpret_cast<float4*>(smem0);   // [16][SEG] padded (0..33024)
    unsigned short* Ahi = reinterpret_cast<unsigned short*>(smem0);  // [32][AS] 0..8704
    unsigned short* Alo = Ahi + QB * AS;                             // 8704..17408
    unsigned short* Hhi = Alo + QB * AS;                             // 17408..26112
    unsigned short* Hlo = Hhi + QB * AS;                             // 26112..34816
    unsigned short* outb = reinterpret_cast<unsigned short*>(smem0) + 16512;  // byte 33024, [32][16]
    unsigned short* tieb = outb + QB * 16;                                    // byte 34048, [32][16]
    // lifetimes: pts (stage..phase D) | outb/tieb (phase D..gather; above pts) |
    // Ahi/Alo (gather..L1) | Hhi/Hlo (L1 epilogue..L2; overwrites dead pts tail/outb)

    const int x     = blockIdx.x;
    const int b     = x & 15;
    const int chunk = x >> 4;                       // 0..63
    const int tid   = threadIdx.x;                  // 0..511
    const int lane  = tid & 63;
    const int w     = tid >> 6;                     // 0..7
    const int sub   = lane & 15;                    // lane within 16-lane group
    const int qg    = lane >> 4;                    // query group within wave (0..3)
    const int q     = w * 4 + qg;                   // 0..31
    const int g     = chunk * QB + q;

    // ---- stage xyz + |p|^2 into padded layout: mem idx = i + (i>>7)
    const float* xb = xyz + (size_t)b * Gn * 3;
    for (int i = tid; i < Gn; i += 512) {
        float px = xb[i * 3 + 0], py = xb[i * 3 + 1], pz = xb[i * 3 + 2];
        pts[i + (i >> 7)] = make_float4(px, py, pz, px * px + py * py + pz * pz);
    }
    __syncthreads();

    const float4 me = pts[g + (g >> 7)];
    const float4* seg = pts + sub * SEG;            // lane's padded 128-pt segment

    // ---- phase A: per-lane top-2 over first 32 segment pts -> exact 16th of
    // 32 candidates -> conservative T0 (>= exact T; phase C recovers exact T)
    float m1 = INFINITY, m2 = INFINITY;
    #pragma unroll
    for (int j = 0; j < 32; j += 2) {
        float4 p0 = seg[j + 0];                     // imm-offset ds_read_b128
        float4 p1 = seg[j + 1];
        float v0 = dist2(me, p0);
        float v1 = dist2(me, p1);
        m2 = med3f(v0, m1, m2); m1 = fminf(m1, v0); // exact top-2 update
        m2 = med3f(v1, m1, m2); m1 = fminf(m1, v1);
    }
    float d[16];
    #pragma unroll
    for (int t = 2; t < 16; ++t) d[t] = INFINITY;
    d[0] = m1; d[1] = m2;                            // sorted ascending
    merge16(d);
    const float T0 = d[15];                          // 16th smallest of 32 cands

    // ---- phase B: filter scan -> register bitmask (bit j <-> segment pt j)
    unsigned mw[4];
    #pragma unroll
    for (int wd = 0; wd < 4; ++wd) {
        unsigned mm = 0;
        #pragma unroll
        for (int j = 0; j < 32; j += 2) {
            float4 p0 = seg[wd * 32 + j + 0];       // imm-offset ds_read_b128
            float4 p1 = seg[wd * 32 + j + 1];
            mm |= (dist2(me, p0) <= T0) ? (1u << (j + 0)) : 0u;
            mm |= (dist2(me, p1) <= T0) ? (1u << (j + 1)) : 0u;
        }
        mw[wd] = mm;
    }
    unsigned long long blo = mw[0] | ((unsigned long long)mw[1] << 32);
    unsigned long long bhi = mw[2] | ((unsigned long long)mw[3] << 32);

    // ---- phase C: exact top16 of survivors (own bits, no cross-lane) -> exact T
    #pragma unroll
    for (int t = 0; t < 16; ++t) d[t] = INFINITY;
    {
        unsigned long long m = blo;
        while (m) {
            int p = __builtin_ctzll(m); m &= m - 1;
            ins16(d, dist2(me, seg[p]));
        }
        m = bhi;
        while (m) {
            int p = 64 + __builtin_ctzll(m); m &= m - 1;
            ins16(d, dist2(me, seg[p]));
        }
    }
    merge16(d);
    const float T = d[15];

    // ---- phase D: emit index set (group-max rounds, INF padding; ballots)
    int myc = __popcll(blo) + __popcll(bhi);
    int mymax = myc;
    #pragma unroll
    for (int m = 1; m < 16; m <<= 1) {
        int o = __shfl_xor(mymax, m);
        mymax = (o > mymax) ? o : mymax;
    }
    const unsigned lowm = (1u << sub) - 1;
    const int shft = lane & 48;                     // group base bit
    const int hbase = sub << 7;                     // output index base
    int nl = 0, nt = 0;
    for (int i = 0; i < mymax; ++i) {
        int h = 0; float v = INFINITY;
        if ((blo | bhi) != 0ull) {
            int p;
            if (blo) { p = __builtin_ctzll(blo); blo &= blo - 1; }
            else     { p = 64 + __builtin_ctzll(bhi); bhi &= bhi - 1; }
            h = hbase + p;                           // global point id
            v = dist2(me, seg[p]);
        }
        bool pl = (v < T), pt = (v == T);
        unsigned long long ml = __ballot(pl);
        unsigned long long mt = __ballot(pt);
        unsigned gml = (unsigned)(ml >> shft) & 0xFFFFu;
        unsigned gmt = (unsigned)(mt >> shft) & 0xFFFFu;
        if (pl) outb[q * 16 + nl + __popc(gml & lowm)] = (unsigned short)h;  // nl_total <= 15
        if (pt) { int pp = nt + __popc(gmt & lowm); if (pp < 16) tieb[q * 16 + pp] = (unsigned short)h; }
        nl += __popc(gml);
        nt += __popc(gmt);
    }
    if (sub == 0) {
        int mfill = nl;                              // < 16
        int need  = 16 - mfill;
        int tc = (nt > 16) ? 16 : nt;
        for (int s = 0; s < need; ++s) {
            int best = 0x7fffffff, bp = -1;
            for (int u = 0; u < tc; ++u) {
                int vv = tieb[q * 16 + u];
                if (vv < best) { best = vv; bp = u; }
            }
            if (bp >= 0) { tieb[q * 16 + bp] = 0xFFFF; outb[q * 16 + mfill + s] = (unsigned short)best; }
        }
    }
    __syncthreads();                                 // pts dead; outb ready (above pts window)

    // ---- gather + L2 pool: half-wave per query, float4 lanes (512B coalesced)
    // indices read 4-at-a-time (ds_read_b64); accumulation order 0..15.
    const float4* fb4 = (const float4*)(feat + (size_t)b * Gn * Cn);
    const int cl = lane & 31;
    #pragma unroll
    for (int pass = 0; pass < 2; ++pass) {
        int qq = w * 4 + pass * 2 + (lane >> 5);
        float4 a = make_float4(0.f, 0.f, 0.f, 0.f);
        #pragma unroll
        for (int qt = 0; qt < 4; ++qt) {
            ushort4 h4 = *(const ushort4*)&outb[qq * 16 + qt * 4];
            float4 f0 = fb4[(size_t)h4.x * 32 + cl];
            float4 f1 = fb4[(size_t)h4.y * 32 + cl];
            float4 f2 = fb4[(size_t)h4.z * 32 + cl];
            float4 f3 = fb4[(size_t)h4.w * 32 + cl];
            a.x = fmaf(f0.x, f0.x, a.x); a.y = fmaf(f0.y, f0.y, a.y);
            a.z = fmaf(f0.z, f0.z, a.z); a.w = fmaf(f0.w, f0.w, a.w);
            a.x = fmaf(f1.x, f1.x, a.x); a.y = fmaf(f1.y, f1.y, a.y);
            a.z = fmaf(f1.z, f1.z, a.z); a.w = fmaf(f1.w, f1.w, a.w);
            a.x = fmaf(f2.x, f2.x, a.x); a.y = fmaf(f2.y, f2.y, a.y);
            a.z = fmaf(f2.z, f2.z, a.z); a.w = fmaf(f2.w, f2.w, a.w);
            a.x = fmaf(f3.x, f3.x, a.x); a.y = fmaf(f3.y, f3.y, a.y);
            a.z = fmaf(f3.z, f3.z, a.z); a.w = fmaf(f3.w, f3.w, a.w);
        }
        float r0 = sqrtf(a.x), r1 = sqrtf(a.y), r2 = sqrtf(a.z), r3 = sqrtf(a.w);
        unsigned short h0 = f2bf(r0), h1 = f2bf(r1), h2 = f2bf(r2), h3 = f2bf(r3);
        ushort4 hv = make_ushort4(h0, h1, h2, h3);
        ushort4 lv = make_ushort4(f2bf(r0 - bf2f(h0)), f2bf(r1 - bf2f(h1)),
                                  f2bf(r2 - bf2f(h2)), f2bf(r3 - bf2f(h3)));
        *(ushort4*)&Ahi[qq * AS + cl * 4] = hv;
        *(ushort4*)&Alo[qq * AS + cl * 4] = lv;
    }
    __syncthreads();                                 // A ready; outb/tieb dead

    // ---- MLP via split-bf16 MFMA, ONE f32x4 acc (sequential col-blocks) ----
    // wave w: rows rowg..rowg+15 (rowg=(w&1)*16), cols colg0..colg0+31
    // A-frag: lane l -> A[rowg+(l&15)][kk + (l>>4)*8 + j]  (contiguous bf16x8)
    // B-frag: lane l -> Wt[colg0+cb*16+(l&15)][kk + (l>>4)*8 + j] (contiguous)
    // C/D:    lane l, reg r -> C[(l>>4)*4 + r][l&15]   (m89-verified)
    const int l15  = lane & 15;
    const int kofs = (lane >> 4) * 8;
    const int rowg = (w & 1) * 16;
    const int colg0 = (w >> 1) * 32;

    // ---- layer 1: H = gelu(A @ W1 + b1) -> Hhi/Hlo (separate buffer, no alias)
    #pragma unroll 1
    for (int cb = 0; cb < 2; ++cb) {
        float bv = b1[colg0 + cb * 16 + l15];
        f32x4 acc = (f32x4){bv, bv, bv, bv};
        #pragma unroll
        for (int kk = 0; kk < 128; kk += 32) {
            bf16x8 ah = *(const bf16x8*)&Ahi[(rowg + l15) * AS + kk + kofs];
            bf16x8 al = *(const bf16x8*)&Alo[(rowg + l15) * AS + kk + kofs];
            const unsigned short* wp = wt + (size_t)(colg0 + cb * 16 + l15) * 128 + kk + kofs;
            bf16x8 bh = *(const bf16x8*)wp;
            bf16x8 bl = *(const bf16x8*)(wp + 16384);
            acc = __builtin_amdgcn_mfma_f32_16x16x32_bf16(ah, bh, acc, 0, 0, 0);
            acc = __builtin_amdgcn_mfma_f32_16x16x32_bf16(ah, bl, acc, 0, 0, 0);
            acc = __builtin_amdgcn_mfma_f32_16x16x32_bf16(al, bh, acc, 0, 0, 0);
        }
        #pragma unroll
        for (int r = 0; r < 4; ++r) {
            float gv = gelu_exact(acc[r]);
            unsigned short h = f2bf(gv);
            int row = rowg + (lane >> 4) * 4 + r;
            int col = colg0 + cb * 16 + l15;
            Hhi[row * AS + col] = h;
            Hlo[row * AS + col] = f2bf(gv - bf2f(h));
        }
    }
    __syncthreads();                            // H tile complete (all waves)

    // ---- layer 2: out = H @ W2 + b2 (store each col-block directly)
    const size_t orow0 = (size_t)b * Gn + (size_t)chunk * QB + rowg + (lane >> 4) * 4;
    #pragma unroll 1
    for (int cb = 0; cb < 2; ++cb) {
        float bv = b2[colg0 + cb * 16 + l15];
        f32x4 acc = (f32x4){bv, bv, bv, bv};
        #pragma unroll
        for (int kk = 0; kk < 128; kk += 32) {
            bf16x8 ah = *(const bf16x8*)&Hhi[(rowg + l15) * AS + kk + kofs];
            bf16x8 al = *(const bf16x8*)&Hlo[(rowg + l15) * AS + kk + kofs];
            const unsigned short* wp = wt + 32768 + (size_t)(colg0 + cb * 16 + l15) * 128 + kk + kofs;
            bf16x8 bh = *(const bf16x8*)wp;
            bf16x8 bl = *(const bf16x8*)(wp + 16384);
            acc = __builtin_amdgcn_mfma_f32_16x16x32_bf16(ah, bh, acc, 0, 0, 0);
            acc = __builtin_amdgcn_mfma_f32_16x16x32_bf16(ah, bl, acc, 0, 0, 0);
            acc = __builtin_amdgcn_mfma_f32_16x16x32_bf16(al, bh, acc, 0, 0, 0);
        }
        #pragma unroll
        for (int r = 0; r < 4; ++r) {
            out[(orow0 + r) * Cn + colg0 + cb * 16 + l15] = acc[r];
        }
    }
}

// ---------------------------------------------------------------------------
extern "C" void kernel_launch(void* const* d_in, const int* in_sizes, int n_in,
                              void* d_out, int out_size, void* d_ws, size_t ws_size,
                              hipStream_t stream) {
    const float* xyz  = (const float*)d_in[0];
    const float* feat = (const float*)d_in[1];
    const float* W1   = (const float*)d_in[2];
    const float* b1   = (const float*)d_in[3];
    const float* W2   = (const float*)d_in[4];
    const float* b2   = (const float*)d_in[5];
    float* out = (float*)d_out;
    unsigned short* wt = (unsigned short*)d_ws;    // 128 KB: Wt1 hi/lo, Wt2 hi/lo

    prep_w<<<64, 256, 0, stream>>>(W1, W2, wt);
    fused_kernel<<<1024, 512, 0, stream>>>(xyz, feat, b1, b2, wt, out);
}

// Round 14
// 154.402 us; speedup vs baseline: 1.1761x; 1.1761x over previous
//
#include <hip/hip_runtime.h>
#include <math.h>

#define Bn 16
#define Gn 2048
#define Cn 128
#define Kn 16
#define QB 32       // queries per block
#define AS 136      // A/H-tile row stride in bf16 elems: 272B = 17*16B (aligned, 2-way banks)

typedef __attribute__((ext_vector_type(8))) short bf16x8;
typedef __attribute__((ext_vector_type(4))) float f32x4;

__device__ __forceinline__ unsigned short f2bf(float x) {   // RNE fp32->bf16
    unsigned int u = __float_as_uint(x);
    unsigned int r = (u + 0x7fffu + ((u >> 16) & 1u)) >> 16;
    return (unsigned short)r;
}
__device__ __forceinline__ float bf2f(unsigned short h) {
    return __uint_as_float(((unsigned int)h) << 16);
}

__device__ __forceinline__ float med3f(float a, float b, float c) {
#if __has_builtin(__builtin_amdgcn_fmed3f)
    return __builtin_amdgcn_fmed3f(a, b, c);
#else
    return fmaxf(fminf(a, b), fminf(fmaxf(a, b), c));
#endif
}

// BIT-IDENTICAL in every phase (fp-consistent ranking incl. tie detection).
__device__ __forceinline__ float dist2(const float4 me, const float4 p) {
    float dot = fmaf(me.z, p.z, fmaf(me.y, p.y, me.x * p.x));
    return fmaf(-2.0f, dot, me.w + p.w);
}

__device__ __forceinline__ void ins16(float (&d)[16], float v) {
    float prev = d[0];
    d[0] = fminf(d[0], v);
    #pragma unroll
    for (int t = 1; t < 16; ++t) { float cur = d[t]; d[t] = med3f(v, prev, cur); prev = cur; }
}

// exact bitonic min-merge of sorted d[16] across the 16 lanes of a group.
// In-place: pairs (t,15-t) disjoint; both shfl reads precede writes.
__device__ __forceinline__ void merge16(float (&d)[16]) {
    #pragma unroll
    for (int m = 1; m < 16; m <<= 1) {
        #pragma unroll
        for (int t = 0; t < 8; ++t) {
            float sa = __shfl_xor(d[15 - t], m);    // partner's d[15-t]
            float sb = __shfl_xor(d[t], m);         // partner's d[t]
            d[t]      = fminf(d[t], sa);
            d[15 - t] = fminf(d[15 - t], sb);
        }
        #pragma unroll
        for (int k = 8; k; k >>= 1) {
            #pragma unroll
            for (int t = 0; t < 16; ++t)
                if (!(t & k)) {
                    float lo = fminf(d[t], d[t + k]);
                    float hi = fmaxf(d[t], d[t + k]);
                    d[t] = lo; d[t + k] = hi;
                }
        }
    }
}

// ascending bitonic sort of one value per lane across an aligned 16-lane group
// (shfl_xor masks < 16 never cross the 16-lane boundary).
__device__ __forceinline__ float bsort16(float v, int sub) {
    #pragma unroll
    for (int k = 2; k <= 16; k <<= 1) {
        #pragma unroll
        for (int j = k >> 1; j >= 1; j >>= 1) {
            float pv = __shfl_xor(v, j);
            bool keepmin = (((sub & j) == 0) == ((sub & k) == 0));
            float mn = fminf(v, pv), mx = fmaxf(v, pv);
            v = keepmin ? mn : mx;
        }
    }
    return v;
}

__device__ __forceinline__ float gelu_exact(float x) {
    return 0.5f * x * (1.0f + erff(x * 0.70710678118654752440f));
}

// ---------------------------------------------------------------------------
// prep_w: W[k][n] fp32 -> Wt[n][k] split bf16 (hi/lo) in workspace.
// ws layout (ushorts): Wt1_hi[128*128] | Wt1_lo | Wt2_hi | Wt2_lo  (128 KB)
// ---------------------------------------------------------------------------
__global__ __launch_bounds__(256) void prep_w(const float* __restrict__ W1,
                                              const float* __restrict__ W2,
                                              unsigned short* __restrict__ ws) {
    int t = blockIdx.x * 256 + threadIdx.x;     // 0..16383 (grid 64)
    if (t < 16384) {
        int k = t >> 7, n = t & 127;
        float w = W1[t];
        unsigned short h = f2bf(w);
        unsigned short l = f2bf(w - bf2f(h));   // Dekker split: w-hi exact in fp32
        ws[n * 128 + k]          = h;
        ws[16384 + n * 128 + k]  = l;
        w = W2[t];
        h = f2bf(w);
        l = f2bf(w - bf2f(h));
        ws[32768 + n * 128 + k]  = h;
        ws[49152 + n * 128 + k]  = l;
    }
}

// ---------------------------------------------------------------------------
// Fully fused: KNN (sample->filter->select) + gather/L2-pool + MFMA MLP.
// 1024 blocks x 512 threads; b = x&15; chunk = x>>4 (0..63); 32 q/block.
// KNN = R12's blocked layout + arithmetic stagger (measured best, 89us;
// R13's imm-offset full unroll raised VGPR 60->72, occupancy 38->22%, dur
// +26us -- register-lean changes only from here).
// PHASE A (R14): per-lane top-2 scan, then BITONIC-PAIR SELECTION: sort the
// 16 m1's and 16 m2's (bsort16, 1 val/lane), 16th of two sorted 16-arrays =
// min over split candidates {max(A[s],B[14-s]) s=0..14; min(A[15],B[15])}.
// Same 32-candidate multiset as R12's merge16 path => bit-identical T0 =>
// identical survivors => identical output. ~105 ops vs ~440, d[16] no
// longer live in A/B.
// No min-waves bound (R4/R6: forcing it => 32/32 unified split + spills).
// MLP: single f32x4 acc, sequential col-blocks, H in separate LDS buffer;
// split-bf16 MFMA 16x16x32 (Ahi*Bhi + Ahi*Blo + Alo*Bhi, err ~2^-17).
// ---------------------------------------------------------------------------
__global__ __launch_bounds__(512) void fused_kernel(const float* __restrict__ xyz,
                                                    const float* __restrict__ feat,
                                                    const float* __restrict__ b1,
                                                    const float* __restrict__ b2,
                                                    const unsigned short* __restrict__ wt,
                                                    float* __restrict__ out) {
    __shared__ __align__(16) float smem0[8704];       // 34816 B
    float4* pts = reinterpret_cast<float4*>(smem0);   // [2048] xyz + |p|^2 (0..32768)
    unsigned short* Ahi = reinterpret_cast<unsigned short*>(smem0);  // [32][AS] 0..8704
    unsigned short* Alo = Ahi + QB * AS;                             // 8704..17408
    unsigned short* Hhi = Alo + QB * AS;                             // 17408..26112
    unsigned short* Hlo = Hhi + QB * AS;                             // 26112..34816
    unsigned short* outb = reinterpret_cast<unsigned short*>(smem0) + 16384;  // byte 32768, [32][16]
    unsigned short* tieb = outb + QB * 16;                                    // byte 33792, [32][16]
    // lifetimes: pts (stage..phase D) | outb/tieb (phase D..gather) |
    // Ahi/Alo (gather..L1) | Hhi/Hlo (L1 epilogue..L2; overwrites dead outb/tieb)

    const int x     = blockIdx.x;
    const int b     = x & 15;
    const int chunk = x >> 4;                       // 0..63
    const int tid   = threadIdx.x;                  // 0..511
    const int lane  = tid & 63;
    const int w     = tid >> 6;                     // 0..7
    const int sub   = lane & 15;                    // lane within 16-lane group
    const int qg    = lane >> 4;                    // query group within wave (0..3)
    const int q     = w * 4 + qg;                   // 0..31
    const int g     = chunk * QB + q;

    // ---- stage xyz + |p|^2
    const float* xb = xyz + (size_t)b * Gn * 3;
    for (int i = tid; i < Gn; i += 512) {
        float px = xb[i * 3 + 0], py = xb[i * 3 + 1], pz = xb[i * 3 + 2];
        pts[i] = make_float4(px, py, pz, px * px + py * py + pz * pz);
    }
    __syncthreads();

    const float4 me = pts[g];
    const int base = sub << 7;                      // lane's 128-point segment
    const int c    = (37 * sub) & 127;              // bank stagger

    // ---- phase A: per-lane top-2 scan -> bitonic-pair select 16th of 32 -> T0
    float m1 = INFINITY, m2 = INFINITY;
    for (int j = 0; j < 32; j += 2) {
        float4 p0 = pts[base + ((j + 0 + c) & 127)];
        float4 p1 = pts[base + ((j + 1 + c) & 127)];
        float v0 = dist2(me, p0);
        float v1 = dist2(me, p1);
        m2 = med3f(v0, m1, m2); m1 = fminf(m1, v0);   // exact top-2 update
        m2 = med3f(v1, m1, m2); m1 = fminf(m1, v1);
    }
    {
        float A = bsort16(m1, sub);                  // A[sub] ascending
        float B = bsort16(m2, sub);                  // B[sub] ascending
        float Brev = __shfl(B, 14 - sub, 16);        // B[14-sub] (unused at sub=15)
        float cand = (sub == 15) ? fminf(A, B) : fmaxf(A, Brev);
        #pragma unroll
        for (int m = 1; m < 16; m <<= 1) cand = fminf(cand, __shfl_xor(cand, m));
        m1 = cand;                                   // T0 in m1
    }
    const float T0 = m1;                             // exact 16th of 32 candidates

    // ---- phase B: filter scan -> register bitmask (scan-order bits, exact)
    unsigned mw[4];
    #pragma unroll
    for (int wd = 0; wd < 4; ++wd) {
        unsigned m = 0;
        #pragma unroll
        for (int j = 0; j < 32; j += 2) {
            int t0 = wd * 32 + j;
            float4 p0 = pts[base + ((t0 + 0 + c) & 127)];
            float4 p1 = pts[base + ((t0 + 1 + c) & 127)];
            m |= (dist2(me, p0) <= T0) ? (1u << (j + 0)) : 0u;
            m |= (dist2(me, p1) <= T0) ? (1u << (j + 1)) : 0u;
        }
        mw[wd] = m;
    }
    unsigned long long blo = mw[0] | ((unsigned long long)mw[1] << 32);
    unsigned long long bhi = mw[2] | ((unsigned long long)mw[3] << 32);

    // ---- phase C: exact top16 of survivors (own bits, no cross-lane) -> exact T
    float d[16];
    #pragma unroll
    for (int t = 0; t < 16; ++t) d[t] = INFINITY;
    {
        unsigned long long m = blo;
        while (m) {
            int p = __builtin_ctzll(m); m &= m - 1;
            int h = base + ((p + c) & 127);
            ins16(d, dist2(me, pts[h]));
        }
        m = bhi;
        while (m) {
            int p = 64 + __builtin_ctzll(m); m &= m - 1;
            int h = base + ((p + c) & 127);
            ins16(d, dist2(me, pts[h]));
        }
    }
    merge16(d);
    const float T = d[15];

    // ---- phase D: emit index set (group-max rounds, INF padding; ballots)
    int myc = __popcll(blo) + __popcll(bhi);
    int mymax = myc;
    #pragma unroll
    for (int m = 1; m < 16; m <<= 1) {
        int o = __shfl_xor(mymax, m);
        mymax = (o > mymax) ? o : mymax;
    }
    const unsigned lowm = (1u << sub) - 1;
    const int shft = lane & 48;                     // group base bit
    int nl = 0, nt = 0;
    for (int i = 0; i < mymax; ++i) {
        int h = 0; float v = INFINITY;
        if ((blo | bhi) != 0ull) {
            int p;
            if (blo) { p = __builtin_ctzll(blo); blo &= blo - 1; }
            else     { p = 64 + __builtin_ctzll(bhi); bhi &= bhi - 1; }
            h = base + ((p + c) & 127);
            v = dist2(me, pts[h]);
        }
        bool pl = (v < T), pt = (v == T);
        unsigned long long ml = __ballot(pl);
        unsigned long long mt = __ballot(pt);
        unsigned gml = (unsigned)(ml >> shft) & 0xFFFFu;
        unsigned gmt = (unsigned)(mt >> shft) & 0xFFFFu;
        if (pl) outb[q * 16 + nl + __popc(gml & lowm)] = (unsigned short)h;  // nl_total <= 15
        if (pt) { int pp = nt + __popc(gmt & lowm); if (pp < 16) tieb[q * 16 + pp] = (unsigned short)h; }
        nl += __popc(gml);
        nt += __popc(gmt);
    }
    if (sub == 0) {
        int mfill = nl;                              // < 16
        int need  = 16 - mfill;
        int tc = (nt > 16) ? 16 : nt;
        for (int s = 0; s < need; ++s) {
            int best = 0x7fffffff, bp = -1;
            for (int u = 0; u < tc; ++u) {
                int vv = tieb[q * 16 + u];
                if (vv < best) { best = vv; bp = u; }
            }
            if (bp >= 0) { tieb[q * 16 + bp] = 0xFFFF; outb[q * 16 + mfill + s] = (unsigned short)best; }
        }
    }
    __syncthreads();                                 // pts dead; outb ready (above pts window)

    // ---- gather + L2 pool: half-wave per query, float4 lanes (512B coalesced)
    // 2-neighbor chunks; accumulation order = neighbors 0..15 sequentially.
    // bf16 split via v_cvt_pk_bf16_f32 (RNE, matches f2bf bit-exactly).
    const float4* fb4 = (const float4*)(feat + (size_t)b * Gn * Cn);
    const int cl = lane & 31;
    #pragma unroll
    for (int pass = 0; pass < 2; ++pass) {
        int qq = w * 4 + pass * 2 + (lane >> 5);
        float4 a = make_float4(0.f, 0.f, 0.f, 0.f);
        #pragma unroll
        for (int qt = 0; qt < 8; ++qt) {
            int hs[2]; float4 f[2];
            #pragma unroll
            for (int k = 0; k < 2; ++k) hs[k] = outb[qq * 16 + qt * 2 + k];
            #pragma unroll
            for (int k = 0; k < 2; ++k) f[k] = fb4[(size_t)hs[k] * 32 + cl];
            #pragma unroll
            for (int k = 0; k < 2; ++k) {
                a.x = fmaf(f[k].x, f[k].x, a.x);
                a.y = fmaf(f[k].y, f[k].y, a.y);
                a.z = fmaf(f[k].z, f[k].z, a.z);
                a.w = fmaf(f[k].w, f[k].w, a.w);
            }
        }
        float r0 = sqrtf(a.x), r1 = sqrtf(a.y), r2 = sqrtf(a.z), r3 = sqrtf(a.w);
        unsigned hp0, hp1, lp0, lp1;
        asm("v_cvt_pk_bf16_f32 %0, %1, %2" : "=v"(hp0) : "v"(r0), "v"(r1));
        asm("v_cvt_pk_bf16_f32 %0, %1, %2" : "=v"(hp1) : "v"(r2), "v"(r3));
        float l0 = r0 - __uint_as_float(hp0 << 16);
        float l1 = r1 - __uint_as_float(hp0 & 0xffff0000u);
        float l2 = r2 - __uint_as_float(hp1 << 16);
        float l3 = r3 - __uint_as_float(hp1 & 0xffff0000u);
        asm("v_cvt_pk_bf16_f32 %0, %1, %2" : "=v"(lp0) : "v"(l0), "v"(l1));
        asm("v_cvt_pk_bf16_f32 %0, %1, %2" : "=v"(lp1) : "v"(l2), "v"(l3));
        *(uint2*)&Ahi[qq * AS + cl * 4] = make_uint2(hp0, hp1);
        *(uint2*)&Alo[qq * AS + cl * 4] = make_uint2(lp0, lp1);
    }
    __syncthreads();                                 // A ready; outb/tieb dead

    // ---- MLP via split-bf16 MFMA, ONE f32x4 acc (sequential col-blocks) ----
    // wave w: rows rowg..rowg+15 (rowg=(w&1)*16), cols colg0..colg0+31
    // A-frag: lane l -> A[rowg+(l&15)][kk + (l>>4)*8 + j]  (contiguous bf16x8)
    // B-frag: lane l -> Wt[colg0+cb*16+(l&15)][kk + (l>>4)*8 + j] (contiguous)
    // C/D:    lane l, reg r -> C[(l>>4)*4 + r][l&15]   (m89-verified)
    const int l15  = lane & 15;
    const int kofs = (lane >> 4) * 8;
    const int rowg = (w & 1) * 16;
    const int colg0 = (w >> 1) * 32;

    // ---- layer 1: H = gelu(A @ W1 + b1) -> Hhi/Hlo (separate buffer, no alias)
    #pragma unroll 1
    for (int cb = 0; cb < 2; ++cb) {
        float bv = b1[colg0 + cb * 16 + l15];
        f32x4 acc = (f32x4){bv, bv, bv, bv};
        #pragma unroll
        for (int kk = 0; kk < 128; kk += 32) {
            bf16x8 ah = *(const bf16x8*)&Ahi[(rowg + l15) * AS + kk + kofs];
            bf16x8 al = *(const bf16x8*)&Alo[(rowg + l15) * AS + kk + kofs];
            const unsigned short* wp = wt + (size_t)(colg0 + cb * 16 + l15) * 128 + kk + kofs;
            bf16x8 bh = *(const bf16x8*)wp;
            bf16x8 bl = *(const bf16x8*)(wp + 16384);
            acc = __builtin_amdgcn_mfma_f32_16x16x32_bf16(ah, bh, acc, 0, 0, 0);
            acc = __builtin_amdgcn_mfma_f32_16x16x32_bf16(ah, bl, acc, 0, 0, 0);
            acc = __builtin_amdgcn_mfma_f32_16x16x32_bf16(al, bh, acc, 0, 0, 0);
        }
        #pragma unroll
        for (int r = 0; r < 4; ++r) {
            float gv = gelu_exact(acc[r]);
            unsigned short h = f2bf(gv);
            int row = rowg + (lane >> 4) * 4 + r;
            int col = colg0 + cb * 16 + l15;
            Hhi[row * AS + col] = h;
            Hlo[row * AS + col] = f2bf(gv - bf2f(h));
        }
    }
    __syncthreads();                            // H tile complete (all waves)

    // ---- layer 2: out = H @ W2 + b2 (store each col-block directly)
    const size_t orow0 = (size_t)b * Gn + (size_t)chunk * QB + rowg + (lane >> 4) * 4;
    #pragma unroll 1
    for (int cb = 0; cb < 2; ++cb) {
        float bv = b2[colg0 + cb * 16 + l15];
        f32x4 acc = (f32x4){bv, bv, bv, bv};
        #pragma unroll
        for (int kk = 0; kk < 128; kk += 32) {
            bf16x8 ah = *(const bf16x8*)&Hhi[(rowg + l15) * AS + kk + kofs];
            bf16x8 al = *(const bf16x8*)&Hlo[(rowg + l15) * AS + kk + kofs];
            const unsigned short* wp = wt + 32768 + (size_t)(colg0 + cb * 16 + l15) * 128 + kk + kofs;
            bf16x8 bh = *(const bf16x8*)wp;
            bf16x8 bl = *(const bf16x8*)(wp + 16384);
            acc = __builtin_amdgcn_mfma_f32_16x16x32_bf16(ah, bh, acc, 0, 0, 0);
            acc = __builtin_amdgcn_mfma_f32_16x16x32_bf16(ah, bl, acc, 0, 0, 0);
            acc = __builtin_amdgcn_mfma_f32_16x16x32_bf16(al, bh, acc, 0, 0, 0);
        }
        #pragma unroll
        for (int r = 0; r < 4; ++r) {
            out[(orow0 + r) * Cn + colg0 + cb * 16 + l15] = acc[r];
        }
    }
}

// ---------------------------------------------------------------------------
extern "C" void kernel_launch(void* const* d_in, const int* in_sizes, int n_in,
                              void* d_out, int out_size, void* d_ws, size_t ws_size,
                              hipStream_t stream) {
    const float* xyz  = (const float*)d_in[0];
    const float* feat = (const float*)d_in[1];
    const float* W1   = (const float*)d_in[2];
    const float* b1   = (const float*)d_in[3];
    const float* W2   = (const float*)d_in[4];
    const float* b2   = (const float*)d_in[5];
    float* out = (float*)d_out;
    unsigned short* wt = (unsigned short*)d_ws;    // 128 KB: Wt1 hi/lo, Wt2 hi/lo

    prep_w<<<64, 256, 0, stream>>>(W1, W2, wt);
    fused_kernel<<<1024, 512, 0, stream>>>(xyz, feat, b1, b2, wt, out);
}

// Round 15
// 140.164 us; speedup vs baseline: 1.2956x; 1.1016x over previous
//
#include <hip/hip_runtime.h>
#include <math.h>

#define Bn 16
#define Gn 2048
#define Cn 128
#define Kn 16
#define QB 32       // queries per block
#define SSEG 144    // padded+duplicated segment stride in float4 (128 pts + first 16 dup)
#define AS 136      // A/H-tile row stride in bf16 elems: 272B = 17*16B (aligned, 2-way banks)

typedef __attribute__((ext_vector_type(8))) short bf16x8;
typedef __attribute__((ext_vector_type(4))) float f32x4;

__device__ __forceinline__ unsigned short f2bf(float x) {   // RNE fp32->bf16
    unsigned int u = __float_as_uint(x);
    unsigned int r = (u + 0x7fffu + ((u >> 16) & 1u)) >> 16;
    return (unsigned short)r;
}
__device__ __forceinline__ float bf2f(unsigned short h) {
    return __uint_as_float(((unsigned int)h) << 16);
}

__device__ __forceinline__ float med3f(float a, float b, float c) {
#if __has_builtin(__builtin_amdgcn_fmed3f)
    return __builtin_amdgcn_fmed3f(a, b, c);
#else
    return fmaxf(fminf(a, b), fminf(fmaxf(a, b), c));
#endif
}

// BIT-IDENTICAL in every phase (fp-consistent ranking incl. tie detection).
__device__ __forceinline__ float dist2(const float4 me, const float4 p) {
    float dot = fmaf(me.z, p.z, fmaf(me.y, p.y, me.x * p.x));
    return fmaf(-2.0f, dot, me.w + p.w);
}

__device__ __forceinline__ void ins16(float (&d)[16], float v) {
    float prev = d[0];
    d[0] = fminf(d[0], v);
    #pragma unroll
    for (int t = 1; t < 16; ++t) { float cur = d[t]; d[t] = med3f(v, prev, cur); prev = cur; }
}

// exact bitonic min-merge of sorted d[16] across the 16 lanes of a group.
// In-place: pairs (t,15-t) disjoint; both shfl reads precede writes.
// ILP-wide (16 independent ops per stage) -- R14 lesson: serial shfl chains
// (bsort16) lose at 4 waves/SIMD even with fewer instructions.
__device__ __forceinline__ void merge16(float (&d)[16]) {
    #pragma unroll
    for (int m = 1; m < 16; m <<= 1) {
        #pragma unroll
        for (int t = 0; t < 8; ++t) {
            float sa = __shfl_xor(d[15 - t], m);    // partner's d[15-t]
            float sb = __shfl_xor(d[t], m);         // partner's d[t]
            d[t]      = fminf(d[t], sa);
            d[15 - t] = fminf(d[15 - t], sb);
        }
        #pragma unroll
        for (int k = 8; k; k >>= 1) {
            #pragma unroll
            for (int t = 0; t < 16; ++t)
                if (!(t & k)) {
                    float lo = fminf(d[t], d[t + k]);
                    float hi = fmaxf(d[t], d[t + k]);
                    d[t] = lo; d[t + k] = hi;
                }
        }
    }
}

__device__ __forceinline__ float gelu_exact(float x) {
    return 0.5f * x * (1.0f + erff(x * 0.70710678118654752440f));
}

// ---------------------------------------------------------------------------
// prep_w: W[k][n] fp32 -> Wt[n][k] split bf16 (hi/lo) in workspace.
// ws layout (ushorts): Wt1_hi[128*128] | Wt1_lo | Wt2_hi | Wt2_lo  (128 KB)
// ---------------------------------------------------------------------------
__global__ __launch_bounds__(256) void prep_w(const float* __restrict__ W1,
                                              const float* __restrict__ W2,
                                              unsigned short* __restrict__ ws) {
    int t = blockIdx.x * 256 + threadIdx.x;     // 0..16383 (grid 64)
    if (t < 16384) {
        int k = t >> 7, n = t & 127;
        float w = W1[t];
        unsigned short h = f2bf(w);
        unsigned short l = f2bf(w - bf2f(h));   // Dekker split: w-hi exact in fp32
        ws[n * 128 + k]          = h;
        ws[16384 + n * 128 + k]  = l;
        w = W2[t];
        h = f2bf(w);
        l = f2bf(w - bf2f(h));
        ws[32768 + n * 128 + k]  = h;
        ws[49152 + n * 128 + k]  = l;
    }
}

// ---------------------------------------------------------------------------
// Fully fused: KNN (sample->filter->select) + gather/L2-pool + MFMA MLP.
// 1024 blocks x 512 threads; b = x&15; chunk = x>>4 (0..63); 32 q/block.
// R15 = R12 base (best, 89us) with WRAP-FREE LINEAR SEGMENT SCAN:
// each lane's 128-pt segment stored at stride SSEG=144 float4 with the
// first 16 points duplicated at the tail, so the scan [sub, sub+128) is
// linear (no per-point (j+c)&127 math). Stagger is structural: start=sub
// -> bank=(4*sub+4j)%32, 8 bank-phases x 2 lanes = 2-way (free, m136);
// the 4 query groups read identical addresses (broadcast). Decode in C/D:
// h = (sub<<7) | ((sub+p)&127). Register discipline (R13 lesson: full
// unroll + imm offsets -> load clustering -> 72 VGPR -> occupancy cliff):
// inner scans '#pragma unroll 4' (<=4 loads in flight), chunk loop rolled.
// T0 = exact 16th of 32 per-lane-top-2 candidates (conservative; phase C
// recovers exact T => output set exact).
// No min-waves bound (R4/R6: forcing it => 32/32 unified split + spills).
// MLP: single f32x4 acc, sequential col-blocks, H in separate LDS buffer;
// split-bf16 MFMA 16x16x32 (Ahi*Bhi + Ahi*Blo + Alo*Bhi, err ~2^-17).
// ---------------------------------------------------------------------------
__global__ __launch_bounds__(512) void fused_kernel(const float* __restrict__ xyz,
                                                    const float* __restrict__ feat,
                                                    const float* __restrict__ b1,
                                                    const float* __restrict__ b2,
                                                    const unsigned short* __restrict__ wt,
                                                    float* __restrict__ out) {
    __shared__ __align__(16) float smem0[9728];       // 38912 B
    float4* pts = reinterpret_cast<float4*>(smem0);   // [16][SSEG] padded (0..36864)
    unsigned short* Ahi = reinterpret_cast<unsigned short*>(smem0);  // [32][AS] 0..8704
    unsigned short* Alo = Ahi + QB * AS;                             // 8704..17408
    unsigned short* Hhi = Alo + QB * AS;                             // 17408..26112
    unsigned short* Hlo = Hhi + QB * AS;                             // 26112..34816
    unsigned short* outb = reinterpret_cast<unsigned short*>(smem0) + 18432;  // byte 36864, [32][16]
    unsigned short* tieb = outb + QB * 16;                                    // byte 37888, [32][16]
    // lifetimes: pts (stage..gather start... phase D) | outb/tieb (phase D..gather;
    // above pts) | Ahi/Alo (gather..L1, overlays dead pts) | Hhi/Hlo (L1..L2)

    const int x     = blockIdx.x;
    const int b     = x & 15;
    const int chunk = x >> 4;                       // 0..63
    const int tid   = threadIdx.x;                  // 0..511
    const int lane  = tid & 63;
    const int w     = tid >> 6;                     // 0..7
    const int sub   = lane & 15;                    // lane within 16-lane group
    const int qg    = lane >> 4;                    // query group within wave (0..3)
    const int q     = w * 4 + qg;                   // 0..31
    const int g     = chunk * QB + q;

    // ---- stage xyz + |p|^2 (padded layout; first 16 of each seg duplicated)
    const float* xb = xyz + (size_t)b * Gn * 3;
    for (int i = tid; i < Gn; i += 512) {
        float px = xb[i * 3 + 0], py = xb[i * 3 + 1], pz = xb[i * 3 + 2];
        float4 v = make_float4(px, py, pz, px * px + py * py + pz * pz);
        int seg = i >> 7, slot = i & 127;
        pts[seg * SSEG + slot] = v;
        if (slot < 16) pts[seg * SSEG + 128 + slot] = v;
    }
    __syncthreads();

    const float4 me = pts[(g >> 7) * SSEG + (g & 127)];
    const float4* seg = pts + sub * SSEG + sub;     // lane's linear 128-pt window

    // ---- phase A: per-lane top-2 over first 32 window pts -> exact 16th of
    // 32 candidates -> conservative T0 (>= exact T; phase C recovers exact T)
    float m1 = INFINITY, m2 = INFINITY;
    #pragma unroll 4
    for (int j = 0; j < 32; ++j) {
        float v = dist2(me, seg[j]);
        m2 = med3f(v, m1, m2);                      // exact top-2 update
        m1 = fminf(m1, v);
    }
    float d[16];
    #pragma unroll
    for (int t = 2; t < 16; ++t) d[t] = INFINITY;
    d[0] = m1; d[1] = m2;                            // sorted ascending
    merge16(d);
    const float T0 = d[15];                          // 16th smallest of 32 cands

    // ---- phase B: filter scan -> register bitmask (bit p <-> window pt p)
    unsigned mw[4];
    #pragma unroll 1
    for (int wd = 0; wd < 4; ++wd) {
        unsigned mm = 0;
        #pragma unroll 4
        for (int j = 0; j < 32; ++j) {
            float v = dist2(me, seg[wd * 32 + j]);
            mm |= (v <= T0) ? (1u << j) : 0u;
        }
        mw[wd] = mm;
    }
    unsigned long long blo = mw[0] | ((unsigned long long)mw[1] << 32);
    unsigned long long bhi = mw[2] | ((unsigned long long)mw[3] << 32);

    // ---- phase C: exact top16 of survivors (own bits, no cross-lane) -> exact T
    #pragma unroll
    for (int t = 0; t < 16; ++t) d[t] = INFINITY;
    {
        unsigned long long m = blo;
        while (m) {
            int p = __builtin_ctzll(m); m &= m - 1;
            ins16(d, dist2(me, seg[p]));
        }
        m = bhi;
        while (m) {
            int p = 64 + __builtin_ctzll(m); m &= m - 1;
            ins16(d, dist2(me, seg[p]));
        }
    }
    merge16(d);
    const float T = d[15];

    // ---- phase D: emit index set (group-max rounds, INF padding; ballots)
    int myc = __popcll(blo) + __popcll(bhi);
    int mymax = myc;
    #pragma unroll
    for (int m = 1; m < 16; m <<= 1) {
        int o = __shfl_xor(mymax, m);
        mymax = (o > mymax) ? o : mymax;
    }
    const unsigned lowm = (1u << sub) - 1;
    const int shft = lane & 48;                     // group base bit
    int nl = 0, nt = 0;
    for (int i = 0; i < mymax; ++i) {
        int h = 0; float v = INFINITY;
        if ((blo | bhi) != 0ull) {
            int p;
            if (blo) { p = __builtin_ctzll(blo); blo &= blo - 1; }
            else     { p = 64 + __builtin_ctzll(bhi); bhi &= bhi - 1; }
            h = (sub << 7) | ((sub + p) & 127);      // global point id
            v = dist2(me, seg[p]);
        }
        bool pl = (v < T), pt = (v == T);
        unsigned long long ml = __ballot(pl);
        unsigned long long mt = __ballot(pt);
        unsigned gml = (unsigned)(ml >> shft) & 0xFFFFu;
        unsigned gmt = (unsigned)(mt >> shft) & 0xFFFFu;
        if (pl) outb[q * 16 + nl + __popc(gml & lowm)] = (unsigned short)h;  // nl_total <= 15
        if (pt) { int pp = nt + __popc(gmt & lowm); if (pp < 16) tieb[q * 16 + pp] = (unsigned short)h; }
        nl += __popc(gml);
        nt += __popc(gmt);
    }
    if (sub == 0) {
        int mfill = nl;                              // < 16
        int need  = 16 - mfill;
        int tc = (nt > 16) ? 16 : nt;
        for (int s = 0; s < need; ++s) {
            int best = 0x7fffffff, bp = -1;
            for (int u = 0; u < tc; ++u) {
                int vv = tieb[q * 16 + u];
                if (vv < best) { best = vv; bp = u; }
            }
            if (bp >= 0) { tieb[q * 16 + bp] = 0xFFFF; outb[q * 16 + mfill + s] = (unsigned short)best; }
        }
    }
    __syncthreads();                                 // pts dead; outb ready (above pts window)

    // ---- gather + L2 pool: half-wave per query, float4 lanes (512B coalesced)
    // 2-neighbor chunks; accumulation order = outb order (set is exact top-16).
    const float4* fb4 = (const float4*)(feat + (size_t)b * Gn * Cn);
    const int cl = lane & 31;
    #pragma unroll
    for (int pass = 0; pass < 2; ++pass) {
        int qq = w * 4 + pass * 2 + (lane >> 5);
        float4 a = make_float4(0.f, 0.f, 0.f, 0.f);
        #pragma unroll
        for (int qt = 0; qt < 8; ++qt) {
            int hs[2]; float4 f[2];
            #pragma unroll
            for (int k = 0; k < 2; ++k) hs[k] = outb[qq * 16 + qt * 2 + k];
            #pragma unroll
            for (int k = 0; k < 2; ++k) f[k] = fb4[(size_t)hs[k] * 32 + cl];
            #pragma unroll
            for (int k = 0; k < 2; ++k) {
                a.x = fmaf(f[k].x, f[k].x, a.x);
                a.y = fmaf(f[k].y, f[k].y, a.y);
                a.z = fmaf(f[k].z, f[k].z, a.z);
                a.w = fmaf(f[k].w, f[k].w, a.w);
            }
        }
        float r0 = sqrtf(a.x), r1 = sqrtf(a.y), r2 = sqrtf(a.z), r3 = sqrtf(a.w);
        unsigned short h0 = f2bf(r0), h1 = f2bf(r1), h2 = f2bf(r2), h3 = f2bf(r3);
        ushort4 hv = make_ushort4(h0, h1, h2, h3);
        ushort4 lv = make_ushort4(f2bf(r0 - bf2f(h0)), f2bf(r1 - bf2f(h1)),
                                  f2bf(r2 - bf2f(h2)), f2bf(r3 - bf2f(h3)));
        *(ushort4*)&Ahi[qq * AS + cl * 4] = hv;
        *(ushort4*)&Alo[qq * AS + cl * 4] = lv;
    }
    __syncthreads();                                 // A ready; outb/tieb dead

    // ---- MLP via split-bf16 MFMA, ONE f32x4 acc (sequential col-blocks) ----
    // wave w: rows rowg..rowg+15 (rowg=(w&1)*16), cols colg0..colg0+31
    // A-frag: lane l -> A[rowg+(l&15)][kk + (l>>4)*8 + j]  (contiguous bf16x8)
    // B-frag: lane l -> Wt[colg0+cb*16+(l&15)][kk + (l>>4)*8 + j] (contiguous)
    // C/D:    lane l, reg r -> C[(l>>4)*4 + r][l&15]   (m89-verified)
    const int l15  = lane & 15;
    const int kofs = (lane >> 4) * 8;
    const int rowg = (w & 1) * 16;
    const int colg0 = (w >> 1) * 32;

    // ---- layer 1: H = gelu(A @ W1 + b1) -> Hhi/Hlo (separate buffer, no alias)
    #pragma unroll 1
    for (int cb = 0; cb < 2; ++cb) {
        float bv = b1[colg0 + cb * 16 + l15];
        f32x4 acc = (f32x4){bv, bv, bv, bv};
        #pragma unroll
        for (int kk = 0; kk < 128; kk += 32) {
            bf16x8 ah = *(const bf16x8*)&Ahi[(rowg + l15) * AS + kk + kofs];
            bf16x8 al = *(const bf16x8*)&Alo[(rowg + l15) * AS + kk + kofs];
            const unsigned short* wp = wt + (size_t)(colg0 + cb * 16 + l15) * 128 + kk + kofs;
            bf16x8 bh = *(const bf16x8*)wp;
            bf16x8 bl = *(const bf16x8*)(wp + 16384);
            acc = __builtin_amdgcn_mfma_f32_16x16x32_bf16(ah, bh, acc, 0, 0, 0);
            acc = __builtin_amdgcn_mfma_f32_16x16x32_bf16(ah, bl, acc, 0, 0, 0);
            acc = __builtin_amdgcn_mfma_f32_16x16x32_bf16(al, bh, acc, 0, 0, 0);
        }
        #pragma unroll
        for (int r = 0; r < 4; ++r) {
            float gv = gelu_exact(acc[r]);
            unsigned short h = f2bf(gv);
            int row = rowg + (lane >> 4) * 4 + r;
            int col = colg0 + cb * 16 + l15;
            Hhi[row * AS + col] = h;
            Hlo[row * AS + col] = f2bf(gv - bf2f(h));
        }
    }
    __syncthreads();                            // H tile complete (all waves)

    // ---- layer 2: out = H @ W2 + b2 (store each col-block directly)
    const size_t orow0 = (size_t)b * Gn + (size_t)chunk * QB + rowg + (lane >> 4) * 4;
    #pragma unroll 1
    for (int cb = 0; cb < 2; ++cb) {
        float bv = b2[colg0 + cb * 16 + l15];
        f32x4 acc = (f32x4){bv, bv, bv, bv};
        #pragma unroll
        for (int kk = 0; kk < 128; kk += 32) {
            bf16x8 ah = *(const bf16x8*)&Hhi[(rowg + l15) * AS + kk + kofs];
            bf16x8 al = *(const bf16x8*)&Hlo[(rowg + l15) * AS + kk + kofs];
            const unsigned short* wp = wt + 32768 + (size_t)(colg0 + cb * 16 + l15) * 128 + kk + kofs;
            bf16x8 bh = *(const bf16x8*)wp;
            bf16x8 bl = *(const bf16x8*)(wp + 16384);
            acc = __builtin_amdgcn_mfma_f32_16x16x32_bf16(ah, bh, acc, 0, 0, 0);
            acc = __builtin_amdgcn_mfma_f32_16x16x32_bf16(ah, bl, acc, 0, 0, 0);
            acc = __builtin_amdgcn_mfma_f32_16x16x32_bf16(al, bh, acc, 0, 0, 0);
        }
        #pragma unroll
        for (int r = 0; r < 4; ++r) {
            out[(orow0 + r) * Cn + colg0 + cb * 16 + l15] = acc[r];
        }
    }
}

// ---------------------------------------------------------------------------
extern "C" void kernel_launch(void* const* d_in, const int* in_sizes, int n_in,
                              void* d_out, int out_size, void* d_ws, size_t ws_size,
                              hipStream_t stream) {
    const float* xyz  = (const float*)d_in[0];
    const float* feat = (const float*)d_in[1];
    const float* W1   = (const float*)d_in[2];
    const float* b1   = (const float*)d_in[3];
    const float* W2   = (const float*)d_in[4];
    const float* b2   = (const float*)d_in[5];
    float* out = (float*)d_out;
    unsigned short* wt = (unsigned short*)d_ws;    // 128 KB: Wt1 hi/lo, Wt2 hi/lo

    prep_w<<<64, 256, 0, stream>>>(W1, W2, wt);
    fused_kernel<<<1024, 512, 0, stream>>>(xyz, feat, b1, b2, wt, out);
}